// Round 1
// baseline (137.951 us; speedup 1.0000x reference)
//
#include <hip/hip_runtime.h>

#define HW (512 * 512)          // 262144 elements per (batch, channel) row
#define BATCH 64
#define NROWS (BATCH * 3)       // 192
#define NB 100
#define HIST_CHUNKS 16          // blocks per row in hist pass
#define NORM_CHUNKS 32          // blocks per row in normalize pass

// ---------------- Pass 1: per-(batch,channel) 100-bin histogram ----------------
__global__ __launch_bounds__(256) void hist_kernel(const float* __restrict__ lab,
                                                   unsigned int* __restrict__ ghist) {
    __shared__ unsigned int sh[4 * NB];   // one sub-histogram per wave
    for (int i = threadIdx.x; i < 4 * NB; i += 256) sh[i] = 0;
    __syncthreads();

    const int row   = blockIdx.x / HIST_CHUNKS;   // b*3 + c
    const int chunk = blockIdx.x % HIST_CHUNKS;
    const int c     = row % 3;

    // histc parameters (match JAX float32 math exactly)
    const float lo = (c == 0) ? 0.0f   : -128.0f;
    const float hi = (c == 0) ? 100.0f : 127.0f;
    const float bs = (c == 0) ? 1.0f   : 2.55f;   // (hi-lo)/100 in f32

    unsigned int* wh = &sh[(threadIdx.x >> 6) * NB];

    const int n4 = HW / 4 / HIST_CHUNKS;          // float4 per block (4096)
    const float4* p = (const float4*)(lab + (size_t)row * HW) + (size_t)chunk * n4;

    for (int i = threadIdx.x; i < n4; i += 256) {
        float4 v = p[i];
        float xs[4] = {v.x, v.y, v.z, v.w};
#pragma unroll
        for (int k = 0; k < 4; ++k) {
            float x = xs[k];
            if (x >= lo && x <= hi) {                       // histc: outside range ignored
                int idx = (int)floorf((x - lo) / bs);       // f32 true division
                idx = idx > (NB - 1) ? (NB - 1) : idx;      // x == hi -> last bin
                atomicAdd(&wh[idx], 1u);
            }
        }
    }
    __syncthreads();

    for (int i = threadIdx.x; i < NB; i += 256) {
        unsigned int s = sh[i] + sh[NB + i] + sh[2 * NB + i] + sh[3 * NB + i];
        if (s) atomicAdd(&ghist[row * NB + i], s);
    }
}

// ---------------- Pass 2: peaks -> per-(b,c) affine coefficients ----------------
// L: second peak (top_k tie-break: lower index wins);  A/B: argmax (first occurrence)
__global__ void peaks_kernel(const unsigned int* __restrict__ ghist,
                             const float* __restrict__ ref_l,
                             const float* __restrict__ ref_a,
                             const float* __restrict__ ref_b,
                             float* __restrict__ coeffs) {
    int b = blockIdx.x * blockDim.x + threadIdx.x;
    if (b >= BATCH) return;
    const unsigned int* h = ghist + (size_t)b * 3 * NB;

    // L channel: second-highest bin.
    {
        long best = -1, sec = -1;
        int bi = 0, si = 0;
        for (int i = 0; i < NB; ++i) {
            long cnt = (long)h[i];
            if (cnt > best)      { sec = best; si = bi; best = cnt; bi = i; }
            else if (cnt > sec)  { sec = cnt;  si = i; }
        }
        float pL  = (si + 0.5f) * 1.0f;                 // lo = 0, bs = 1
        float mul = ref_l[0] / pL;
        coeffs[b * 6 + 0] = mul * (1.0f / 200.0f);
        coeffs[b * 6 + 1] = 0.5f;                       // 100/200
    }
    // A and B channels: primary peak.
    for (int c = 1; c < 3; ++c) {
        const unsigned int* hc = h + c * NB;
        long best = -1; int bi = 0;
        for (int i = 0; i < NB; ++i) {
            long cnt = (long)hc[i];
            if (cnt > best) { best = cnt; bi = i; }
        }
        float p   = -128.0f + (bi + 0.5f) * 2.55f;
        float r   = (c == 1) ? ref_a[0] : ref_b[0];
        float mul = r / p;
        coeffs[b * 6 + c * 2]     = mul * (1.0f / 255.0f);
        coeffs[b * 6 + c * 2 + 1] = 128.0f / 255.0f;
    }
}

// ---------------- Pass 3: elementwise affine ----------------
__global__ __launch_bounds__(256) void norm_kernel(const float* __restrict__ lab,
                                                   const float* __restrict__ coeffs,
                                                   float* __restrict__ out) {
    const int row   = blockIdx.x / NORM_CHUNKS;    // b*3 + c
    const int chunk = blockIdx.x % NORM_CHUNKS;
    const float s = coeffs[row * 2];
    const float o = coeffs[row * 2 + 1];

    const int n4 = HW / 4 / NORM_CHUNKS;           // 2048
    const size_t base = (size_t)row * (HW / 4) + (size_t)chunk * n4;
    const float4* ip = (const float4*)lab + base;
    float4*       op = (float4*)out + base;

    for (int i = threadIdx.x; i < n4; i += 256) {
        float4 v = ip[i];
        v.x = fmaf(v.x, s, o);
        v.y = fmaf(v.y, s, o);
        v.z = fmaf(v.z, s, o);
        v.w = fmaf(v.w, s, o);
        op[i] = v;
    }
}

extern "C" void kernel_launch(void* const* d_in, const int* in_sizes, int n_in,
                              void* d_out, int out_size, void* d_ws, size_t ws_size,
                              hipStream_t stream) {
    const float* lab   = (const float*)d_in[0];
    const float* ref_l = (const float*)d_in[1];
    const float* ref_a = (const float*)d_in[2];
    const float* ref_b = (const float*)d_in[3];
    float* out = (float*)d_out;

    unsigned int* ghist = (unsigned int*)d_ws;                        // 192*100 u32
    float* coeffs = (float*)((char*)d_ws + NROWS * NB * sizeof(unsigned int)); // 192*2 f32

    // ws is poisoned (0xAA) and not re-poisoned between replays: zero every call.
    hipMemsetAsync(ghist, 0, NROWS * NB * sizeof(unsigned int), stream);

    hipLaunchKernelGGL(hist_kernel, dim3(NROWS * HIST_CHUNKS), dim3(256), 0, stream,
                       lab, ghist);
    hipLaunchKernelGGL(peaks_kernel, dim3(1), dim3(64), 0, stream,
                       ghist, ref_l, ref_a, ref_b, coeffs);
    hipLaunchKernelGGL(norm_kernel, dim3(NROWS * NORM_CHUNKS), dim3(256), 0, stream,
                       lab, coeffs, out);
}

// Round 3
// 111.726 us; speedup vs baseline: 1.2347x; 1.2347x over previous
//
#include <hip/hip_runtime.h>

#define HW (512 * 512)          // elements per (batch, channel) row
#define BATCH 64
#define NROWS (BATCH * 3)       // 192
#define NB 100
#define NCOPY 16                // LDS sub-histogram copies per block
#define CSTRIDE 101             // copy stride -> 16 distinct banks across copies
#define HIST_CHUNKS 16          // blocks per row in hist pass
#define NORM_CHUNKS 32          // blocks per row in normalize pass

typedef float f32x4 __attribute__((ext_vector_type(4)));  // native vec: nontemporal-builtin OK

// ---------------- Pass 1: per-(row,chunk) partial 100-bin histogram ----------------
template <bool PARTIAL>
__global__ __launch_bounds__(256) void hist_kernel(const float* __restrict__ lab,
                                                   unsigned int* __restrict__ gout) {
    __shared__ unsigned int sh[NCOPY * CSTRIDE];
    for (int i = threadIdx.x; i < NCOPY * CSTRIDE; i += 256) sh[i] = 0;
    __syncthreads();

    const int row   = blockIdx.x / HIST_CHUNKS;   // b*3 + c
    const int chunk = blockIdx.x % HIST_CHUNKS;
    const int c     = row % 3;

    // histc parameters (match reference float32 math exactly)
    const float lo = (c == 0) ? 0.0f   : -128.0f;
    const float hi = (c == 0) ? 100.0f : 127.0f;
    const float bs = (c == 0) ? 1.0f   : 2.55f;

    unsigned int* wh = &sh[(threadIdx.x & (NCOPY - 1)) * CSTRIDE];

    const int n4 = HW / 4 / HIST_CHUNKS;          // 4096 float4 per block
    const f32x4* p = (const f32x4*)(lab + (size_t)row * HW) + (size_t)chunk * n4;

    for (int i = threadIdx.x; i < n4; i += 256) {
        f32x4 v = p[i];
#pragma unroll
        for (int k = 0; k < 4; ++k) {
            float x = v[k];
            if (x >= lo && x <= hi) {                   // histc: outside range ignored
                int idx = (int)floorf((x - lo) / bs);   // f32 true division (exactness)
                idx = idx > (NB - 1) ? (NB - 1) : idx;  // x == hi -> last bin
                atomicAdd(&wh[idx], 1u);
            }
        }
    }
    __syncthreads();

    for (int i = threadIdx.x; i < NB; i += 256) {
        unsigned int s = 0;
#pragma unroll
        for (int j = 0; j < NCOPY; ++j) s += sh[j * CSTRIDE + i];
        if (PARTIAL)
            gout[((size_t)row * HIST_CHUNKS + chunk) * NB + i] = s;  // plain store, no memset needed
        else if (s)
            atomicAdd(&gout[row * NB + i], s);
    }
}

// ---------------- Pass 2: reduce partials, find peaks, emit affine coeffs ----------------
// L: second peak (top_k tie-break: lower index first);  A/B: argmax (first occurrence)
__global__ __launch_bounds__(128) void peaks_kernel(const unsigned int* __restrict__ part,
                                                    int nchunks,
                                                    const float* __restrict__ ref_l,
                                                    const float* __restrict__ ref_a,
                                                    const float* __restrict__ ref_b,
                                                    float* __restrict__ coeffs) {
    __shared__ unsigned int hh[3][NB];
    const int b = blockIdx.x;
    for (int c = 0; c < 3; ++c) {
        if (threadIdx.x < NB) {
            unsigned int s = 0;
            const unsigned int* p = part + (size_t)(b * 3 + c) * nchunks * NB + threadIdx.x;
            for (int k = 0; k < nchunks; ++k) s += p[(size_t)k * NB];  // coalesced across bins
            hh[c][threadIdx.x] = s;
        }
    }
    __syncthreads();

    if (threadIdx.x == 0) {
        // L channel: second-highest bin, jax top_k tie-break semantics.
        long best = -1, sec = -1; int bi = 0, si = 0;
        for (int i = 0; i < NB; ++i) {
            long cnt = (long)hh[0][i];
            if (cnt > best)     { sec = best; si = bi; best = cnt; bi = i; }
            else if (cnt > sec) { sec = cnt;  si = i; }
        }
        float pL = (si + 0.5f);                       // lo = 0, bin = 1
        coeffs[b * 6 + 0] = ref_l[0] / pL * (1.0f / 200.0f);
        coeffs[b * 6 + 1] = 0.5f;
    } else if (threadIdx.x == 1 || threadIdx.x == 2) {
        int c = threadIdx.x;
        long best = -1; int bi = 0;
        for (int i = 0; i < NB; ++i) {
            long cnt = (long)hh[c][i];
            if (cnt > best) { best = cnt; bi = i; }
        }
        float p = -128.0f + (bi + 0.5f) * 2.55f;
        float r = (c == 1) ? ref_a[0] : ref_b[0];
        coeffs[b * 6 + c * 2]     = r / p * (1.0f / 255.0f);
        coeffs[b * 6 + c * 2 + 1] = 128.0f / 255.0f;
    }
}

// ---------------- Pass 3: elementwise affine, non-temporal stores ----------------
__global__ __launch_bounds__(256) void norm_kernel(const float* __restrict__ lab,
                                                   const float* __restrict__ coeffs,
                                                   float* __restrict__ out) {
    const int row   = blockIdx.x / NORM_CHUNKS;
    const int chunk = blockIdx.x % NORM_CHUNKS;
    const float s = coeffs[row * 2];
    const float o = coeffs[row * 2 + 1];

    const int n4 = HW / 4 / NORM_CHUNKS;           // 2048
    const size_t base = (size_t)row * (HW / 4) + (size_t)chunk * n4;
    const f32x4* ip = (const f32x4*)lab + base;
    f32x4*       op = (f32x4*)out + base;

    for (int i = threadIdx.x; i < n4; i += 256) {
        f32x4 v = ip[i];
        v.x = fmaf(v.x, s, o);
        v.y = fmaf(v.y, s, o);
        v.z = fmaf(v.z, s, o);
        v.w = fmaf(v.w, s, o);
        __builtin_nontemporal_store(v, &op[i]);    // don't evict lab from L3
    }
}

extern "C" void kernel_launch(void* const* d_in, const int* in_sizes, int n_in,
                              void* d_out, int out_size, void* d_ws, size_t ws_size,
                              hipStream_t stream) {
    const float* lab   = (const float*)d_in[0];
    const float* ref_l = (const float*)d_in[1];
    const float* ref_a = (const float*)d_in[2];
    const float* ref_b = (const float*)d_in[3];
    float* out = (float*)d_out;

    const size_t part_bytes = (size_t)NROWS * HIST_CHUNKS * NB * sizeof(unsigned int); // 1.23 MB
    const size_t coeff_bytes = BATCH * 6 * sizeof(float);

    if (ws_size >= part_bytes + coeff_bytes) {
        // Partial-histogram path: no memset, no global atomics.
        unsigned int* part = (unsigned int*)d_ws;
        float* coeffs = (float*)((char*)d_ws + part_bytes);

        hipLaunchKernelGGL((hist_kernel<true>), dim3(NROWS * HIST_CHUNKS), dim3(256), 0, stream,
                           lab, part);
        hipLaunchKernelGGL(peaks_kernel, dim3(BATCH), dim3(128), 0, stream,
                           part, HIST_CHUNKS, ref_l, ref_a, ref_b, coeffs);
        hipLaunchKernelGGL(norm_kernel, dim3(NROWS * NORM_CHUNKS), dim3(256), 0, stream,
                           lab, coeffs, out);
    } else {
        // Fallback: single global histogram with atomics (proven path).
        unsigned int* ghist = (unsigned int*)d_ws;                      // 192*100 u32
        float* coeffs = (float*)((char*)d_ws + NROWS * NB * sizeof(unsigned int));

        (void)hipMemsetAsync(ghist, 0, NROWS * NB * sizeof(unsigned int), stream);
        hipLaunchKernelGGL((hist_kernel<false>), dim3(NROWS * HIST_CHUNKS), dim3(256), 0, stream,
                           lab, ghist);
        hipLaunchKernelGGL(peaks_kernel, dim3(BATCH), dim3(128), 0, stream,
                           ghist, 1, ref_l, ref_a, ref_b, coeffs);
        hipLaunchKernelGGL(norm_kernel, dim3(NROWS * NORM_CHUNKS), dim3(256), 0, stream,
                           lab, coeffs, out);
    }
}